// Round 12
// baseline (216.690 us; speedup 1.0000x reference)
//
#include <hip/hip_runtime.h>
#include <math.h>

#define EMB 32

// v5: v3's block-cooperative staging + single barrier, but the barrier is
// moved BEFORE the random-gather chain:
//   idx loads -> weight staging -> __syncthreads -> member idx -> item ->
//   member rows -> compute e0 -> compute e1.
// The barrier's vmcnt(0) drain now only covers the coalesced idx loads and
// the L2-resident weight staging loads -- NOT the 12 random user_emb row
// gathers (v3 drained those at the barrier, max-coupled across 4 waves).
// Gathers issued after the barrier are waited by counted vmcnt at first
// use: e0 compute overlaps e1's in-flight rows, and nothing drains to 0.
// Keeps v4's git-fold (g*it.wa + g.wb = g.(it*wa+wb)) for register savings
// (verified absmax 0.0 in round 6).
// Block = 256 threads (4 waves), 64 groups x 2 elements = 128 elem/block.
// Grid = 1024. __launch_bounds__(256,4): <=128 VGPR -> 16 waves/CU.
__global__ __launch_bounds__(256, 4) void bahdanau_fused(
    const int* __restrict__ group_inputs,   // [B]
    const int* __restrict__ item_inputs,    // [B]
    const int* __restrict__ members,        // [500000][3]
    const float* __restrict__ user_emb,     // [1000000][32]
    const float* __restrict__ item_emb,     // [100000][14]
    const float* __restrict__ genres,       // [100000][18]
    const float* __restrict__ attn_W,       // [128][3]
    const float* __restrict__ attn_b,       // [3]
    const float* __restrict__ pred_W1,      // [96][8]
    const float* __restrict__ pred_b1,      // [8]
    const float* __restrict__ pred_W2,      // [8][1]
    const float* __restrict__ pred_b2,      // [1]
    float* __restrict__ out)                // [B]
{
    __shared__ float s_aWT[3 * 128];   // [k][d]  transposed attn_W
    __shared__ float s_W1T[8 * 96];    // [c][r]  transposed pred_W1
    __shared__ float s_ab[3];
    __shared__ float s_b1[8];
    __shared__ float s_W2[8];
    __shared__ float s_b2[1];

    const int tid = threadIdx.x;
    const int t = tid & 3;                          // dim-slice owner
    const int grp = tid >> 2;                       // 0..63
    const int ebase = blockIdx.x * 128 + grp * 2;   // group's 2 elements
    const int dbase = t * 8;

    // ---- 1. Element indices: issue first (root of the chain) ----
    const int2 gpair = *(const int2*)&group_inputs[ebase];
    const int2 ipair = *(const int2*)&item_inputs[ebase];

    // ---- 2. Block-cooperative weight staging (cheap: ~4.5 iter/thread) ----
    for (int i = tid; i < 3 * 128; i += 256) {
        int k = i >> 7, d = i & 127;
        s_aWT[i] = attn_W[d * 3 + k];
    }
    for (int i = tid; i < 8 * 96; i += 256) {
        int c = i / 96, r = i - c * 96;
        s_W1T[i] = pred_W1[r * 8 + c];
    }
    if (tid < 3) s_ab[tid] = attn_b[tid];
    else if (tid < 11) s_b1[tid - 3] = pred_b1[tid - 3];
    else if (tid < 19) s_W2[tid - 11] = pred_W2[tid - 11];
    else if (tid == 19) s_b2[0] = pred_b2[0];

    // Barrier BEFORE the random gathers: drains only idx + staging loads.
    __syncthreads();

    // ---- 3. Member indices (chain level 2) ----
    const int g0 = gpair.x, g1 = gpair.y;
    const int i0 = ipair.x, i1 = ipair.y;
    int m0[3], m1[3];
#pragma unroll
    for (int j = 0; j < 3; ++j) {
        m0[j] = members[3 * g0 + j];
        m1[j] = members[3 * g1 + j];
    }

    // ---- 4. Item vectors (depend only on level-1 index) ----
    float itv0[8], itv1[8];
#pragma unroll
    for (int i = 0; i < 4; ++i) {
        const int d = dbase + 2 * i;
        const float2* p0 = (d < 14)
            ? (const float2*)(item_emb + (size_t)i0 * 14 + d)
            : (const float2*)(genres   + (size_t)i0 * 18 + (d - 14));
        const float2 a = *p0;
        itv0[2 * i] = a.x; itv0[2 * i + 1] = a.y;
    }
#pragma unroll
    for (int i = 0; i < 4; ++i) {
        const int d = dbase + 2 * i;
        const float2* p1 = (d < 14)
            ? (const float2*)(item_emb + (size_t)i1 * 14 + d)
            : (const float2*)(genres   + (size_t)i1 * 18 + (d - 14));
        const float2 b = *p1;
        itv1[2 * i] = b.x; itv1[2 * i + 1] = b.y;
    }

    // ---- 5. Member row gathers: e0's 6 loads first, then e1's ----
    float mem0[3][8], mem1[3][8];
#pragma unroll
    for (int j = 0; j < 3; ++j) {
        const float4* p0 = (const float4*)(user_emb + (size_t)m0[j] * EMB + dbase);
        float4 a = p0[0], b = p0[1];
        mem0[j][0] = a.x; mem0[j][1] = a.y; mem0[j][2] = a.z; mem0[j][3] = a.w;
        mem0[j][4] = b.x; mem0[j][5] = b.y; mem0[j][6] = b.z; mem0[j][7] = b.w;
    }
#pragma unroll
    for (int j = 0; j < 3; ++j) {
        const float4* p1 = (const float4*)(user_emb + (size_t)m1[j] * EMB + dbase);
        float4 c = p1[0], d = p1[1];
        mem1[j][0] = c.x; mem1[j][1] = c.y; mem1[j][2] = c.z; mem1[j][3] = c.w;
        mem1[j][4] = d.x; mem1[j][5] = d.y; mem1[j][6] = d.z; mem1[j][7] = d.w;
    }

    // ---- 6. Compute element 0 (e1's rows may still be in flight) ----
    float hq0, hq1;
    {
        float aw[3];
#pragma unroll
        for (int k = 0; k < 3; ++k) {
            float a0 = 0.f;
#pragma unroll
            for (int j = 0; j < 3; ++j) {
                const float4* wp = (const float4*)&s_aWT[k * 128 + j * 32 + dbase];
                float4 wl = wp[0], wh = wp[1];
                float w[8] = {wl.x, wl.y, wl.z, wl.w, wh.x, wh.y, wh.z, wh.w};
#pragma unroll
                for (int i = 0; i < 8; ++i) a0 = fmaf(mem0[j][i], w[i], a0);
            }
            const float4* wp = (const float4*)&s_aWT[k * 128 + 96 + dbase];
            float4 wl = wp[0], wh = wp[1];
            float w[8] = {wl.x, wl.y, wl.z, wl.w, wh.x, wh.y, wh.z, wh.w};
#pragma unroll
            for (int i = 0; i < 8; ++i) a0 = fmaf(itv0[i], w[i], a0);
            a0 += __shfl_xor(a0, 1, 4);
            a0 += __shfl_xor(a0, 2, 4);
            aw[k] = a0 + s_ab[k];
        }
        float gv[8];
#pragma unroll
        for (int i = 0; i < 8; ++i)
            gv[i] = aw[0] * mem0[0][i] + aw[1] * mem0[1][i] + aw[2] * mem0[2][i];
        float ph[8];
#pragma unroll
        for (int c = 0; c < 8; ++c) {
            const float4* wpa = (const float4*)&s_W1T[c * 96 + dbase];
            const float4* wpb = (const float4*)&s_W1T[c * 96 + 32 + dbase];
            const float4* wpc = (const float4*)&s_W1T[c * 96 + 64 + dbase];
            float4 al = wpa[0], ah = wpa[1];
            float4 bl = wpb[0], bh = wpb[1];
            float4 cl = wpc[0], ch = wpc[1];
            float wa[8] = {al.x, al.y, al.z, al.w, ah.x, ah.y, ah.z, ah.w};
            float wb[8] = {bl.x, bl.y, bl.z, bl.w, bh.x, bh.y, bh.z, bh.w};
            float wc[8] = {cl.x, cl.y, cl.z, cl.w, ch.x, ch.y, ch.z, ch.w};
            float a0 = 0.f;
#pragma unroll
            for (int i = 0; i < 8; ++i) {
                a0 = fmaf(gv[i], fmaf(itv0[i], wa[i], wb[i]), a0);  // g*it.wa + g.wb
                a0 = fmaf(itv0[i], wc[i], a0);
            }
            ph[c] = a0;
        }
        float y = s_b2[0];
#pragma unroll
        for (int c = 0; c < 8; ++c) {
            float v = ph[c];
            v += __shfl_xor(v, 1, 4);
            v += __shfl_xor(v, 2, 4);
            float h = fmaxf(v + s_b1[c], 0.0f);
            y = fmaf(h, s_W2[c], y);
        }
        hq0 = y;
    }

    // ---- 7. Compute element 1 ----
    {
        float aw[3];
#pragma unroll
        for (int k = 0; k < 3; ++k) {
            float a1 = 0.f;
#pragma unroll
            for (int j = 0; j < 3; ++j) {
                const float4* wp = (const float4*)&s_aWT[k * 128 + j * 32 + dbase];
                float4 wl = wp[0], wh = wp[1];
                float w[8] = {wl.x, wl.y, wl.z, wl.w, wh.x, wh.y, wh.z, wh.w};
#pragma unroll
                for (int i = 0; i < 8; ++i) a1 = fmaf(mem1[j][i], w[i], a1);
            }
            const float4* wp = (const float4*)&s_aWT[k * 128 + 96 + dbase];
            float4 wl = wp[0], wh = wp[1];
            float w[8] = {wl.x, wl.y, wl.z, wl.w, wh.x, wh.y, wh.z, wh.w};
#pragma unroll
            for (int i = 0; i < 8; ++i) a1 = fmaf(itv1[i], w[i], a1);
            a1 += __shfl_xor(a1, 1, 4);
            a1 += __shfl_xor(a1, 2, 4);
            aw[k] = a1 + s_ab[k];
        }
        float gv[8];
#pragma unroll
        for (int i = 0; i < 8; ++i)
            gv[i] = aw[0] * mem1[0][i] + aw[1] * mem1[1][i] + aw[2] * mem1[2][i];
        float ph[8];
#pragma unroll
        for (int c = 0; c < 8; ++c) {
            const float4* wpa = (const float4*)&s_W1T[c * 96 + dbase];
            const float4* wpb = (const float4*)&s_W1T[c * 96 + 32 + dbase];
            const float4* wpc = (const float4*)&s_W1T[c * 96 + 64 + dbase];
            float4 al = wpa[0], ah = wpa[1];
            float4 bl = wpb[0], bh = wpb[1];
            float4 cl = wpc[0], ch = wpc[1];
            float wa[8] = {al.x, al.y, al.z, al.w, ah.x, ah.y, ah.z, ah.w};
            float wb[8] = {bl.x, bl.y, bl.z, bl.w, bh.x, bh.y, bh.z, bh.w};
            float wc[8] = {cl.x, cl.y, cl.z, cl.w, ch.x, ch.y, ch.z, ch.w};
            float a1 = 0.f;
#pragma unroll
            for (int i = 0; i < 8; ++i) {
                a1 = fmaf(gv[i], fmaf(itv1[i], wa[i], wb[i]), a1);
                a1 = fmaf(itv1[i], wc[i], a1);
            }
            ph[c] = a1;
        }
        float y = s_b2[0];
#pragma unroll
        for (int c = 0; c < 8; ++c) {
            float v = ph[c];
            v += __shfl_xor(v, 1, 4);
            v += __shfl_xor(v, 2, 4);
            float h = fmaxf(v + s_b1[c], 0.0f);
            y = fmaf(h, s_W2[c], y);
        }
        hq1 = y;
    }

    // ---- 8. Sigmoid + store (lane t<2 stores element ebase+t) ----
    if (t < 2) {
        float y = (t == 0) ? hq0 : hq1;
        y = 1.0f / (1.0f + expf(-y));
        out[ebase + t] = y;
    }
}

extern "C" void kernel_launch(void* const* d_in, const int* in_sizes, int n_in,
                              void* d_out, int out_size, void* d_ws, size_t ws_size,
                              hipStream_t stream) {
    const int*   group_inputs = (const int*)d_in[0];
    const int*   item_inputs  = (const int*)d_in[1];
    const int*   members      = (const int*)d_in[2];
    const float* user_emb     = (const float*)d_in[3];
    const float* item_emb     = (const float*)d_in[4];
    const float* genres       = (const float*)d_in[5];
    const float* attn_W       = (const float*)d_in[6];
    const float* attn_b       = (const float*)d_in[7];
    const float* pred_W1      = (const float*)d_in[8];
    const float* pred_b1      = (const float*)d_in[9];
    const float* pred_W2      = (const float*)d_in[10];
    const float* pred_b2      = (const float*)d_in[11];
    float* out = (float*)d_out;

    const int B = in_sizes[0];           // 131072
    const int blocks = B / 128;          // 1024 blocks, 128 elements each

    bahdanau_fused<<<blocks, 256, 0, stream>>>(
        group_inputs, item_inputs, members, user_emb, item_emb, genres,
        attn_W, attn_b, pred_W1, pred_b1, pred_W2, pred_b2, out);
}

// Round 17
// 210.095 us; speedup vs baseline: 1.0314x; 1.0314x over previous
//
#include <hip/hip_runtime.h>
#include <math.h>

#define EMB 32

// v6: occupancy experiment. Evidence from v3/v4/v5: barrier/drain semantics
// are irrelevant (v4 no-barrier and v5 cheap-barrier both lost ~8us the same
// way); what wins is v3's chain-first gather injection, and the kernel is
// under-saturated (effective ~1.2TB/s vs multi-TB/s L2/L3 ceilings) ->
// latency/parallelism-bound. Lever: waves/CU 16 -> 24.
//  - q=1: each 4-lane group owns ONE element (was 2). Gather-destination
//    registers drop by 32 floats -> body fits a 85-VGPR budget.
//  - __launch_bounds__(256,6): 6 blocks/CU, 24 waves/CU, 85 VGPR cap.
//  - EXACT v3 issue order preserved: idx -> member idx -> item -> member
//    rows -> weight staging -> barrier -> compute. (v4/v5 showed putting
//    staging VMEM ahead of the random chain costs ~8us.)
//  - keeps float2 item loads + git-fold (both verified absmax 0.0).
// Block = 256 threads (4 waves) = 64 groups x 1 element. Grid = B/64 = 2048.
__global__ __launch_bounds__(256, 6) void bahdanau_fused(
    const int* __restrict__ group_inputs,   // [B]
    const int* __restrict__ item_inputs,    // [B]
    const int* __restrict__ members,        // [500000][3]
    const float* __restrict__ user_emb,     // [1000000][32]
    const float* __restrict__ item_emb,     // [100000][14]
    const float* __restrict__ genres,       // [100000][18]
    const float* __restrict__ attn_W,       // [128][3]
    const float* __restrict__ attn_b,       // [3]
    const float* __restrict__ pred_W1,      // [96][8]
    const float* __restrict__ pred_b1,      // [8]
    const float* __restrict__ pred_W2,      // [8][1]
    const float* __restrict__ pred_b2,      // [1]
    float* __restrict__ out)                // [B]
{
    __shared__ float s_aWT[3 * 128];   // [k][d]  transposed attn_W
    __shared__ float s_W1T[8 * 96];    // [c][r]  transposed pred_W1
    __shared__ float s_ab[3];
    __shared__ float s_b1[8];
    __shared__ float s_W2[8];
    __shared__ float s_b2[1];

    const int tid = threadIdx.x;
    const int t = tid & 3;                          // dim-slice owner
    const int grp = tid >> 2;                       // 0..63
    const int e = blockIdx.x * 64 + grp;            // this group's element
    const int dbase = t * 8;

    // ---- 1. Element indices: root of the chain, issued first ----
    const int g0 = group_inputs[e];
    const int i0 = item_inputs[e];

    // ---- 2. Member indices (chain level 2) ----
    int m0[3];
#pragma unroll
    for (int j = 0; j < 3; ++j) m0[j] = members[3 * g0 + j];

    // ---- 3. Item vector (depends only on level-1 index) ----
    float itv0[8];
#pragma unroll
    for (int i = 0; i < 4; ++i) {
        const int d = dbase + 2 * i;
        const float2* p0 = (d < 14)
            ? (const float2*)(item_emb + (size_t)i0 * 14 + d)
            : (const float2*)(genres   + (size_t)i0 * 18 + (d - 14));
        const float2 a = *p0;
        itv0[2 * i] = a.x; itv0[2 * i + 1] = a.y;
    }

    // ---- 4. Member row gathers (3 x dwordx4-pair, rows 128B-aligned) ----
    float mem0[3][8];
#pragma unroll
    for (int j = 0; j < 3; ++j) {
        const float4* p0 = (const float4*)(user_emb + (size_t)m0[j] * EMB + dbase);
        float4 a = p0[0], b = p0[1];
        mem0[j][0] = a.x; mem0[j][1] = a.y; mem0[j][2] = a.z; mem0[j][3] = a.w;
        mem0[j][4] = b.x; mem0[j][5] = b.y; mem0[j][6] = b.z; mem0[j][7] = b.w;
    }

    // ---- 5. Block-cooperative weight staging (after the chain, as in v3) ----
    for (int i = tid; i < 3 * 128; i += 256) {
        int k = i >> 7, d = i & 127;
        s_aWT[i] = attn_W[d * 3 + k];
    }
    for (int i = tid; i < 8 * 96; i += 256) {
        int c = i / 96, r = i - c * 96;
        s_W1T[i] = pred_W1[r * 8 + c];
    }
    if (tid < 3) s_ab[tid] = attn_b[tid];
    else if (tid < 11) s_b1[tid - 3] = pred_b1[tid - 3];
    else if (tid < 19) s_W2[tid - 11] = pred_W2[tid - 11];
    else if (tid == 19) s_b2[0] = pred_b2[0];
    __syncthreads();

    // ---- 6. Attention logits ----
    float aw[3];
#pragma unroll
    for (int k = 0; k < 3; ++k) {
        float a0 = 0.f;
#pragma unroll
        for (int j = 0; j < 3; ++j) {
            const float4* wp = (const float4*)&s_aWT[k * 128 + j * 32 + dbase];
            float4 wl = wp[0], wh = wp[1];
            float w[8] = {wl.x, wl.y, wl.z, wl.w, wh.x, wh.y, wh.z, wh.w};
#pragma unroll
            for (int i = 0; i < 8; ++i) a0 = fmaf(mem0[j][i], w[i], a0);
        }
        const float4* wp = (const float4*)&s_aWT[k * 128 + 96 + dbase];
        float4 wl = wp[0], wh = wp[1];
        float w[8] = {wl.x, wl.y, wl.z, wl.w, wh.x, wh.y, wh.z, wh.w};
#pragma unroll
        for (int i = 0; i < 8; ++i) a0 = fmaf(itv0[i], w[i], a0);
        a0 += __shfl_xor(a0, 1, 4);
        a0 += __shfl_xor(a0, 2, 4);
        aw[k] = a0 + s_ab[k];
    }

    // ---- 7. g slice + MLP hidden partials (git-fold) ----
    float gv[8];
#pragma unroll
    for (int i = 0; i < 8; ++i)
        gv[i] = aw[0] * mem0[0][i] + aw[1] * mem0[1][i] + aw[2] * mem0[2][i];

    float y = s_b2[0];
#pragma unroll
    for (int c = 0; c < 8; ++c) {
        const float4* wpa = (const float4*)&s_W1T[c * 96 + dbase];
        const float4* wpb = (const float4*)&s_W1T[c * 96 + 32 + dbase];
        const float4* wpc = (const float4*)&s_W1T[c * 96 + 64 + dbase];
        float4 al = wpa[0], ah = wpa[1];
        float4 bl = wpb[0], bh = wpb[1];
        float4 cl = wpc[0], ch = wpc[1];
        float wa[8] = {al.x, al.y, al.z, al.w, ah.x, ah.y, ah.z, ah.w};
        float wb[8] = {bl.x, bl.y, bl.z, bl.w, bh.x, bh.y, bh.z, bh.w};
        float wc[8] = {cl.x, cl.y, cl.z, cl.w, ch.x, ch.y, ch.z, ch.w};
        float a0 = 0.f;
#pragma unroll
        for (int i = 0; i < 8; ++i) {
            a0 = fmaf(gv[i], fmaf(itv0[i], wa[i], wb[i]), a0);  // g*it.wa + g.wb
            a0 = fmaf(itv0[i], wc[i], a0);
        }
        // 4-lane reduce of this hidden unit, then fold into y immediately
        a0 += __shfl_xor(a0, 1, 4);
        a0 += __shfl_xor(a0, 2, 4);
        float h = fmaxf(a0 + s_b1[c], 0.0f);
        y = fmaf(h, s_W2[c], y);
    }

    // ---- 8. Sigmoid + store (lane t==0 stores element e) ----
    if (t == 0) {
        out[e] = 1.0f / (1.0f + expf(-y));
    }
}

extern "C" void kernel_launch(void* const* d_in, const int* in_sizes, int n_in,
                              void* d_out, int out_size, void* d_ws, size_t ws_size,
                              hipStream_t stream) {
    const int*   group_inputs = (const int*)d_in[0];
    const int*   item_inputs  = (const int*)d_in[1];
    const int*   members      = (const int*)d_in[2];
    const float* user_emb     = (const float*)d_in[3];
    const float* item_emb     = (const float*)d_in[4];
    const float* genres       = (const float*)d_in[5];
    const float* attn_W       = (const float*)d_in[6];
    const float* attn_b       = (const float*)d_in[7];
    const float* pred_W1      = (const float*)d_in[8];
    const float* pred_b1      = (const float*)d_in[9];
    const float* pred_W2      = (const float*)d_in[10];
    const float* pred_b2      = (const float*)d_in[11];
    float* out = (float*)d_out;

    const int B = in_sizes[0];           // 131072
    const int blocks = B / 64;           // 2048 blocks, 64 elements each

    bahdanau_fused<<<blocks, 256, 0, stream>>>(
        group_inputs, item_inputs, members, user_emb, item_emb, genres,
        attn_W, attn_b, pred_W1, pred_b1, pred_W2, pred_b2, out);
}